// Round 2
// baseline (332.585 us; speedup 1.0000x reference)
//
#include <hip/hip_runtime.h>
#include <hip/hip_bf16.h>

typedef __hip_bfloat16 bf16;
__device__ __forceinline__ float bf2f(bf16 v) { return __bfloat162float(v); }

typedef __attribute__((ext_vector_type(8))) short short8;
typedef __attribute__((ext_vector_type(4))) float floatx4;

// ===========================================================================
// Direct CSR build over the unified key space k in [0, M):
//   k = e       : edge segment   (values = vertex ids)
//   k = E + v   : vertex segment (values = edge ids)
// offs/cnt: M+1 ints (L2-resident, 480 KB). perm: 2*nnz ints.
// Replaces the old 5-kernel bucketize pipeline (saved ~16 MB traffic +
// LDS-atomic serialization); atomics on 120k counters are ~17/counter max.
// ===========================================================================

__global__ __launch_bounds__(256) void zero_kernel(int* __restrict__ cnt, int n) {
  const int i = blockIdx.x * 256 + threadIdx.x;
  if (i < n) cnt[i] = 0;
}

__global__ __launch_bounds__(256) void hist_kernel(
    const int* __restrict__ vertex, const int* __restrict__ edges,
    int* __restrict__ cnt, int nnz, int E) {
  const int i = (blockIdx.x * 256 + threadIdx.x) * 4;
  if (i + 4 <= nnz) {
    const int4 ev = *(const int4*)&edges[i];
    const int4 vv = *(const int4*)&vertex[i];
    atomicAdd(&cnt[ev.x], 1); atomicAdd(&cnt[E + vv.x], 1);
    atomicAdd(&cnt[ev.y], 1); atomicAdd(&cnt[E + vv.y], 1);
    atomicAdd(&cnt[ev.z], 1); atomicAdd(&cnt[E + vv.z], 1);
    atomicAdd(&cnt[ev.w], 1); atomicAdd(&cnt[E + vv.w], 1);
  } else {
    for (int j = i; j < nnz; ++j) {
      atomicAdd(&cnt[edges[j]], 1);
      atomicAdd(&cnt[E + vertex[j]], 1);
    }
  }
}

// ---- 3-kernel exclusive scan of cnt[0..M) (in place), 1024 elems/block ----
#define SCAN_CHUNK 1024

__global__ __launch_bounds__(256) void scan_part_kernel(
    int* __restrict__ cnt, int* __restrict__ psum, int M) {
  __shared__ int ws[4];
  const int tid  = threadIdx.x;
  const int lane = tid & 63;
  const int wid  = tid >> 6;
  const int base = blockIdx.x * SCAN_CHUNK + tid * 4;

  int c0 = 0, c1 = 0, c2 = 0, c3 = 0;
  if (base + 3 < M) {
    const int4 c = *(const int4*)&cnt[base];
    c0 = c.x; c1 = c.y; c2 = c.z; c3 = c.w;
  } else {
    if (base     < M) c0 = cnt[base];
    if (base + 1 < M) c1 = cnt[base + 1];
    if (base + 2 < M) c2 = cnt[base + 2];
    if (base + 3 < M) c3 = cnt[base + 3];
  }
  const int s = c0 + c1 + c2 + c3;
  int inc = s;
#pragma unroll
  for (int d = 1; d < 64; d <<= 1) {
    const int t = __shfl_up(inc, d, 64);
    if (lane >= d) inc += t;
  }
  if (lane == 63) ws[wid] = inc;
  __syncthreads();
  int wbase = 0;
  for (int w = 0; w < wid; ++w) wbase += ws[w];
  const int excl = wbase + inc - s;

  if (base + 3 < M) {
    int4 o;
    o.x = excl; o.y = excl + c0; o.z = excl + c0 + c1; o.w = excl + c0 + c1 + c2;
    *(int4*)&cnt[base] = o;
  } else {
    if (base     < M) cnt[base]     = excl;
    if (base + 1 < M) cnt[base + 1] = excl + c0;
    if (base + 2 < M) cnt[base + 2] = excl + c0 + c1;
    if (base + 3 < M) cnt[base + 3] = excl + c0 + c1 + c2;
  }
  if (tid == 255) psum[blockIdx.x] = wbase + inc;   // block total
}

__global__ __launch_bounds__(256) void scan_top_kernel(
    const int* __restrict__ psum, int* __restrict__ pbase,
    int* __restrict__ cnt, int nP, int M) {
  __shared__ int ws[4];
  const int tid  = threadIdx.x;
  const int lane = tid & 63;
  const int wid  = tid >> 6;
  const int v = (tid < nP) ? psum[tid] : 0;
  int inc = v;
#pragma unroll
  for (int d = 1; d < 64; d <<= 1) {
    const int t = __shfl_up(inc, d, 64);
    if (lane >= d) inc += t;
  }
  if (lane == 63) ws[wid] = inc;
  __syncthreads();
  int wbase = 0;
  for (int w = 0; w < wid; ++w) wbase += ws[w];
  const int excl = wbase + inc - v;
  if (tid < nP) pbase[tid] = excl;
  if (tid == 255) cnt[M] = wbase + inc;   // sentinel = 2*nnz
}

__global__ __launch_bounds__(256) void scan_apply_kernel(
    int* __restrict__ cnt, int* __restrict__ curs,
    const int* __restrict__ pbase, int M) {
  const int base = blockIdx.x * SCAN_CHUNK + threadIdx.x * 4;
  const int add  = pbase[blockIdx.x];
  if (base + 3 < M) {
    int4 c = *(const int4*)&cnt[base];
    c.x += add; c.y += add; c.z += add; c.w += add;
    *(int4*)&cnt[base]  = c;
    *(int4*)&curs[base] = c;
  } else {
    for (int j = 0; j < 4; ++j)
      if (base + j < M) {
        const int t = cnt[base + j] + add;
        cnt[base + j]  = t;
        curs[base + j] = t;
      }
  }
}

// ---- scatter: perm fill via return-atomics on L2-resident cursors ----
__global__ __launch_bounds__(256) void scatter_kernel(
    const int* __restrict__ vertex, const int* __restrict__ edges,
    int* __restrict__ curs, int* __restrict__ perm, int nnz, int E) {
  const int i = (blockIdx.x * 256 + threadIdx.x) * 4;
  if (i + 4 <= nnz) {
    const int4 ev = *(const int4*)&edges[i];
    const int4 vv = *(const int4*)&vertex[i];
    int p;
    p = atomicAdd(&curs[ev.x], 1);     perm[p] = vv.x;
    p = atomicAdd(&curs[E + vv.x], 1); perm[p] = ev.x;
    p = atomicAdd(&curs[ev.y], 1);     perm[p] = vv.y;
    p = atomicAdd(&curs[E + vv.y], 1); perm[p] = ev.y;
    p = atomicAdd(&curs[ev.z], 1);     perm[p] = vv.z;
    p = atomicAdd(&curs[E + vv.z], 1); perm[p] = ev.z;
    p = atomicAdd(&curs[ev.w], 1);     perm[p] = vv.w;
    p = atomicAdd(&curs[E + vv.w], 1); perm[p] = ev.w;
  } else {
    for (int j = i; j < nnz; ++j) {
      const int e = edges[j], v = vertex[j];
      int p;
      p = atomicAdd(&curs[e], 1);     perm[p] = v;
      p = atomicAdd(&curs[E + v], 1); perm[p] = e;
    }
  }
}

// ===========================================================================
// MFMA GEMM: Xl[N,64] (bf16) = X[N,128] (f32) @ W[128,64] (f32).
// Block = 4 waves; 64-row tile x 64 cols; K=128 via mfma_f32_16x16x32_bf16.
// W^T staged to LDS once/block, B-fragments hoisted to registers.
// A-layout: a[j] = A[m=lane&15][k=quad*8+j]; B: b[j] = B[k=quad*8+j][n=lane&15]
// C/D: col=lane&15, row=quad*4+reg  (verified layouts, learn_hip m89/m120)
// ===========================================================================
__device__ __forceinline__ unsigned int pack_bf16x2(float lo, float hi) {
  bf16 a = __float2bfloat16(lo);
  bf16 b = __float2bfloat16(hi);
  unsigned short ua = *(unsigned short*)&a;
  unsigned short ub = *(unsigned short*)&b;
  return (unsigned int)ua | ((unsigned int)ub << 16);
}

#define XS_STRIDE 136   // ushort; 16B-aligned rows, 2-way-free fragment reads

__global__ __launch_bounds__(256) void gemm_kernel(
    const float* __restrict__ X, const float* __restrict__ W,
    bf16* __restrict__ Xl, int Nrows, int ntiles) {
  __shared__ unsigned short Ws[64 * XS_STRIDE];   // W^T: [n][k] bf16, 17.4 KB
  __shared__ unsigned short Xs[64 * XS_STRIDE];   // [m][k] bf16,     17.4 KB

  const int tid  = threadIdx.x;
  const int wave = tid >> 6;
  const int lane = tid & 63;
  const int quad = lane >> 4;
  const int l15  = lane & 15;

  // Stage W^T (8192 elements, coalesced f32 reads, scalar bf16 LDS writes)
  for (int i = tid; i < 8192; i += 256) {
    const int k = i >> 6, n = i & 63;
    bf16 h = __float2bfloat16(W[i]);
    Ws[n * XS_STRIDE + k] = *(unsigned short*)&h;
  }
  __syncthreads();

  // Hoist B fragments: b[ct][kt] = W[kt*32+quad*8+j][ct*16+l15]
  short8 bfrag[4][4];
#pragma unroll
  for (int ct = 0; ct < 4; ++ct)
#pragma unroll
    for (int kt = 0; kt < 4; ++kt)
      bfrag[ct][kt] = *(const short8*)&Ws[(ct * 16 + l15) * XS_STRIDE + kt * 32 + quad * 8];

  const int r  = tid >> 2;        // staging row 0..63
  const int c0 = (tid & 3) * 32;  // staging col group

  for (int tile = blockIdx.x; tile < ntiles; tile += gridDim.x) {
    const int row0 = tile * 64;
    // Stage 64 rows of X as bf16 (32 floats/thread: 8x float4 -> 4x uint4)
    {
      int rr = row0 + r;
      if (rr >= Nrows) rr = Nrows - 1;
      const float* src = X + (size_t)rr * 128 + c0;
      unsigned short* dst = &Xs[r * XS_STRIDE + c0];
#pragma unroll
      for (int q = 0; q < 4; ++q) {
        const float4 f0 = *(const float4*)(src + q * 8);
        const float4 f1 = *(const float4*)(src + q * 8 + 4);
        uint4 o;
        o.x = pack_bf16x2(f0.x, f0.y);
        o.y = pack_bf16x2(f0.z, f0.w);
        o.z = pack_bf16x2(f1.x, f1.y);
        o.w = pack_bf16x2(f1.z, f1.w);
        *(uint4*)(dst + q * 8) = o;
      }
    }
    __syncthreads();

    // A fragments for this wave's 16 rows
    const int m = wave * 16 + l15;
    short8 afrag[4];
#pragma unroll
    for (int kt = 0; kt < 4; ++kt)
      afrag[kt] = *(const short8*)&Xs[m * XS_STRIDE + kt * 32 + quad * 8];

    floatx4 acc[4];
#pragma unroll
    for (int ct = 0; ct < 4; ++ct) {
      acc[ct] = (floatx4){0.f, 0.f, 0.f, 0.f};
#pragma unroll
      for (int kt = 0; kt < 4; ++kt)
        acc[ct] = __builtin_amdgcn_mfma_f32_16x16x32_bf16(
            afrag[kt], bfrag[ct][kt], acc[ct], 0, 0, 0);
    }

    // Store C: row = row0 + wave*16 + quad*4 + reg, col = ct*16 + l15
    const int rbase_ = row0 + wave * 16 + quad * 4;
#pragma unroll
    for (int ct = 0; ct < 4; ++ct) {
      const int col = ct * 16 + l15;
#pragma unroll
      for (int reg = 0; reg < 4; ++reg) {
        const int row = rbase_ + reg;
        if (row < Nrows) Xl[(size_t)row * 64 + col] = __float2bfloat16(acc[ct][reg]);
      }
    }
    __syncthreads();   // before next tile restages Xs
  }
}

// ===========================================================================
// Gather 1: one wave per hyperedge. Xe[e] = degE[e]*W_edge[e] * sum_v Xl[v]
// ===========================================================================
__global__ __launch_bounds__(256) void gather_e_kernel(
    const bf16* __restrict__ Xl, const int* __restrict__ perm,
    const int* __restrict__ offs, const float* __restrict__ degE,
    const float* __restrict__ W_edge, bf16* __restrict__ Xe, int E) {
  const int gtid = blockIdx.x * 256 + threadIdx.x;
  const int e    = gtid >> 6;
  const int lane = gtid & 63;
  if (e >= E) return;

  const int beg = offs[e];
  const int end = offs[e + 1];
  float acc = 0.f;

  for (int base = beg; base < end; base += 64) {
    const int n = min(64, end - base);
    const int idx = (lane < n) ? perm[base + lane] : 0;
    int jj = 0;
    for (; jj + 4 <= n; jj += 4) {
      const int v0 = __shfl(idx, jj + 0, 64);
      const int v1 = __shfl(idx, jj + 1, 64);
      const int v2 = __shfl(idx, jj + 2, 64);
      const int v3 = __shfl(idx, jj + 3, 64);
      const float f0 = bf2f(Xl[(size_t)v0 * 64 + lane]);
      const float f1 = bf2f(Xl[(size_t)v1 * 64 + lane]);
      const float f2 = bf2f(Xl[(size_t)v2 * 64 + lane]);
      const float f3 = bf2f(Xl[(size_t)v3 * 64 + lane]);
      acc += (f0 + f1) + (f2 + f3);
    }
    for (; jj < n; ++jj) {
      const int v = __shfl(idx, jj, 64);
      acc += bf2f(Xl[(size_t)v * 64 + lane]);
    }
  }
  const float s = degE[e] * W_edge[e];
  Xe[(size_t)e * 64 + lane] = __float2bfloat16(acc * s);
}

// ===========================================================================
// Gather 2: one wave per node. out[v] = degV[v] * sum_e Xe[e]
// ===========================================================================
__global__ __launch_bounds__(256) void gather_v_kernel(
    const bf16* __restrict__ Xe, const int* __restrict__ perm,
    const int* __restrict__ offs, const float* __restrict__ degV,
    float* __restrict__ out, int N, int E) {
  const int gtid = blockIdx.x * 256 + threadIdx.x;
  const int v    = gtid >> 6;
  const int lane = gtid & 63;
  if (v >= N) return;

  const int beg = offs[E + v];
  const int end = offs[E + v + 1];
  float acc = 0.f;

  for (int base = beg; base < end; base += 64) {
    const int n = min(64, end - base);
    const int idx = (lane < n) ? perm[base + lane] : 0;
    int jj = 0;
    for (; jj + 4 <= n; jj += 4) {
      const int e0 = __shfl(idx, jj + 0, 64);
      const int e1 = __shfl(idx, jj + 1, 64);
      const int e2 = __shfl(idx, jj + 2, 64);
      const int e3 = __shfl(idx, jj + 3, 64);
      const float f0 = bf2f(Xe[(size_t)e0 * 64 + lane]);
      const float f1 = bf2f(Xe[(size_t)e1 * 64 + lane]);
      const float f2 = bf2f(Xe[(size_t)e2 * 64 + lane]);
      const float f3 = bf2f(Xe[(size_t)e3 * 64 + lane]);
      acc += (f0 + f1) + (f2 + f3);
    }
    for (; jj < n; ++jj) {
      const int e = __shfl(idx, jj, 64);
      acc += bf2f(Xe[(size_t)e * 64 + lane]);
    }
  }
  __builtin_nontemporal_store(acc * degV[v], &out[(size_t)v * 64 + lane]);
}

// ===========================================================================
extern "C" void kernel_launch(void* const* d_in, const int* in_sizes, int n_in,
                              void* d_out, int out_size, void* d_ws, size_t ws_size,
                              hipStream_t stream) {
  const float* X      = (const float*)d_in[0];
  const int*   vertex = (const int*)d_in[1];
  const int*   edges  = (const int*)d_in[2];
  const float* W      = (const float*)d_in[3];
  const float* degE   = (const float*)d_in[4];
  const float* degV   = (const float*)d_in[5];
  const float* W_edge = (const float*)d_in[6];
  float* out = (float*)d_out;

  const int nnz = in_sizes[1];
  const int E   = in_sizes[4];
  const int N   = in_sizes[5];
  const int M   = E + N;

  char* p = (char*)d_ws;
  auto alloc = [&](size_t bytes) -> void* {
    void* r = (void*)p;
    p += (bytes + 255) & ~(size_t)255;
    return r;
  };
  int*  offs  = (int*)alloc((size_t)(M + 1) * 4);   // cnt -> exclusive offs
  int*  curs  = (int*)alloc((size_t)M * 4);         // scatter cursors
  int*  psum  = (int*)alloc(512 * 4);
  int*  pbase = (int*)alloc(512 * 4);
  int*  perm  = (int*)alloc((size_t)2 * nnz * 4);
  bf16* Xe    = (bf16*)alloc((size_t)E * 64 * 2);
  bf16* Xl    = (bf16*)alloc((size_t)N * 64 * 2);

  const int nP      = (M + SCAN_CHUNK - 1) / SCAN_CHUNK;       // <=256 for M<=256K
  const int iblocks = (nnz / 4 + 255) / 256;                   // hist/scatter grid

  zero_kernel<<<(M + 256) / 256, 256, 0, stream>>>(offs, M + 1);
  hist_kernel<<<iblocks, 256, 0, stream>>>(vertex, edges, offs, nnz, E);
  scan_part_kernel<<<nP, 256, 0, stream>>>(offs, psum, M);
  scan_top_kernel<<<1, 256, 0, stream>>>(psum, pbase, offs, nP, M);
  scan_apply_kernel<<<nP, 256, 0, stream>>>(offs, curs, pbase, M);
  scatter_kernel<<<iblocks, 256, 0, stream>>>(vertex, edges, curs, perm, nnz, E);

  const int ntiles = (N + 63) / 64;
  const int gblocks = ntiles < 512 ? ntiles : 512;
  gemm_kernel<<<gblocks, 256, 0, stream>>>(X, W, Xl, N, ntiles);

  gather_e_kernel<<<(E + 3) / 4, 256, 0, stream>>>(Xl, perm, offs, degE, W_edge, Xe, E);
  gather_v_kernel<<<(N + 3) / 4, 256, 0, stream>>>(Xe, perm, offs, degV, out, N, E);
}